// Round 1
// baseline (80.757 us; speedup 1.0000x reference)
//
#include <hip/hip_runtime.h>

typedef __attribute__((ext_vector_type(8))) short short8;
typedef __attribute__((ext_vector_type(4))) float f32x4;

__device__ __forceinline__ unsigned short f2bf(float f) {
    unsigned u = __builtin_bit_cast(unsigned, f);
    unsigned r = (u + 0x7FFFu + ((u >> 16) & 1u)) >> 16;
    return (unsigned short)r;
}

// ---- fused fp32 -> bf16 conversion: x, w0, w1, w2 (8 elems/thread) ----
__global__ __launch_bounds__(256) void k_convert(
    const float* __restrict__ x,  const float* __restrict__ w0,
    const float* __restrict__ w1, const float* __restrict__ w2,
    unsigned short* __restrict__ xb,  unsigned short* __restrict__ w0b,
    unsigned short* __restrict__ w1b, unsigned short* __restrict__ w2b)
{
    const int nx  = (1024 * 480) / 8;
    const int nw0 = (8 * 512 * 480) / 8;
    const int nw1 = (8 * 512 * 512) / 8;
    const int nw2 = (8 * 311 * 512) / 8;
    int t = blockIdx.x * 256 + threadIdx.x;
    const float* src; unsigned short* dst;
    if (t < nx)              { src = x;  dst = xb;  }
    else if ((t -= nx)  < nw0) { src = w0; dst = w0b; }
    else if ((t -= nw0) < nw1) { src = w1; dst = w1b; }
    else if ((t -= nw1) < nw2) { src = w2; dst = w2b; }
    else return;
    const float4* s4 = (const float4*)src;
    float4 a = s4[2 * t], b = s4[2 * t + 1];
    union { unsigned short u[8]; int4 v; } r;
    r.u[0] = f2bf(a.x); r.u[1] = f2bf(a.y); r.u[2] = f2bf(a.z); r.u[3] = f2bf(a.w);
    r.u[4] = f2bf(b.x); r.u[5] = f2bf(b.y); r.u[6] = f2bf(b.z); r.u[7] = f2bf(b.w);
    ((int4*)dst)[t] = r.v;
}

// ---- batched per-expert NT GEMM: y[e,b,o] = sum_k A[b,k] * W[e,o,k] ----
// A: [1024][K] bf16 row-major; W: [E][N][K] bf16; Y: [E][1024][ldy] fp32
// 128x128 tile, 4 waves (2x2 of 64x64), BK=32, mfma 16x16x32 bf16.
__global__ __launch_bounds__(256) void k_gemm(
    const unsigned short* __restrict__ A,
    const unsigned short* __restrict__ W,
    float* __restrict__ Y,
    int K, int N, int ldy)
{
    __shared__ unsigned short As[128][32];  // 8 KB
    __shared__ unsigned short Bs[128][32];  // 8 KB

    const int e  = blockIdx.z;
    const int bm = blockIdx.y * 128;
    const int on = blockIdx.x * 128;
    const int t  = threadIdx.x;
    const int lane = t & 63;
    const int w  = t >> 6;
    const int wr = w >> 1, wc = w & 1;

    const unsigned short* Wt = W + (size_t)e * N * K;

    f32x4 acc[4][4] = {};

    const int ktn = K / 32;
    for (int kt = 0; kt < ktn; ++kt) {
        const int k0 = kt * 32;
        // stage A-tile and B-tile: 512 chunks of 16B each, 2 per thread per tile
        #pragma unroll
        for (int q = 0; q < 2; ++q) {
            int c   = t + q * 256;
            int r   = c >> 2;          // 0..127
            int col = (c & 3) * 8;     // 0,8,16,24
            *(int4*)&As[r][col] = *(const int4*)&A[(size_t)(bm + r) * K + k0 + col];
            int rb = on + r; if (rb >= N) rb = N - 1;   // clamp for N=311 tail tile
            *(int4*)&Bs[r][col] = *(const int4*)&Wt[(size_t)rb * K + k0 + col];
        }
        __syncthreads();

        short8 af[4], bfr[4];
        #pragma unroll
        for (int fm = 0; fm < 4; ++fm)
            af[fm] = *(const short8*)&As[wr * 64 + fm * 16 + (lane & 15)][(lane >> 4) * 8];
        #pragma unroll
        for (int fn = 0; fn < 4; ++fn)
            bfr[fn] = *(const short8*)&Bs[wc * 64 + fn * 16 + (lane & 15)][(lane >> 4) * 8];
        #pragma unroll
        for (int fm = 0; fm < 4; ++fm)
            #pragma unroll
            for (int fn = 0; fn < 4; ++fn)
                acc[fm][fn] = __builtin_amdgcn_mfma_f32_16x16x32_bf16(
                    af[fm], bfr[fn], acc[fm][fn], 0, 0, 0);
        __syncthreads();
    }

    // epilogue: D[i][j] -> j = lane&15, i = 4*(lane>>4) + r
    float* Ye = Y + (size_t)e * 1024 * ldy;
    #pragma unroll
    for (int fm = 0; fm < 4; ++fm) {
        #pragma unroll
        for (int fn = 0; fn < 4; ++fn) {
            int i0 = bm + wr * 64 + fm * 16 + (lane >> 4) * 4;
            int j  = on + wc * 64 + fn * 16 + (lane & 15);
            if (j < N) {
                #pragma unroll
                for (int r = 0; r < 4; ++r)
                    Ye[(size_t)(i0 + r) * ldy + j] = acc[fm][fn][r];
            }
        }
    }
}

// ---- blend-reduce over experts + bias + (optional ELU), write bf16 or fp32 ----
__global__ __launch_bounds__(256) void k_reduce(
    const float* __restrict__ Y,      // [E][1024][ldy]
    const float* __restrict__ blend,  // [E][1024]
    const float* __restrict__ bias,   // [E][N]
    void* __restrict__ out,
    int N, int ldy, int act, int out_bf16)
{
    int idx = blockIdx.x * 256 + threadIdx.x;
    int total = 1024 * N;
    if (idx >= total) return;
    int b = idx / N, o = idx - b * N;
    float s = 0.f;
    #pragma unroll
    for (int e = 0; e < 8; ++e) {
        float bl = blend[e * 1024 + b];
        s += bl * (Y[((size_t)e * 1024 + b) * ldy + o] + bias[e * N + o]);
    }
    if (act) s = (s > 0.f) ? s : expm1f(s);
    if (out_bf16) ((unsigned short*)out)[(size_t)b * N + o] = f2bf(s);
    else          ((float*)out)[(size_t)b * N + o] = s;
}

extern "C" void kernel_launch(void* const* d_in, const int* in_sizes, int n_in,
                              void* d_out, int out_size, void* d_ws, size_t ws_size,
                              hipStream_t stream) {
    const float* x     = (const float*)d_in[0];
    const float* blend = (const float*)d_in[1];
    const float* w0    = (const float*)d_in[2];
    const float* b0    = (const float*)d_in[3];
    const float* w1    = (const float*)d_in[4];
    const float* b1    = (const float*)d_in[5];
    const float* w2    = (const float*)d_in[6];
    const float* b2    = (const float*)d_in[7];

    char* ws = (char*)d_ws;
    // offsets (bytes), all 16B-aligned
    unsigned short* xb  = (unsigned short*)(ws + 0);         //   983,040 B
    unsigned short* w0b = (unsigned short*)(ws + 983040);    // 3,932,160 B
    unsigned short* w1b = (unsigned short*)(ws + 4915200);   // 4,194,304 B
    unsigned short* w2b = (unsigned short*)(ws + 9109504);   // 2,547,712 B
    unsigned short* h1b = (unsigned short*)(ws + 11657216);  // 1,048,576 B
    unsigned short* h2b = (unsigned short*)(ws + 12705792);  // 1,048,576 B
    float*          y   = (float*)        (ws + 13754368);   // 16,777,216 B
    // total ~29.1 MB

    // 1) convert fp32 -> bf16 (x, w0, w1, w2)
    k_convert<<<2846, 256, 0, stream>>>(x, w0, w1, w2, xb, w0b, w1b, w2b);

    // 2) layer 0: [1024,480] x [8,512,480] -> y, then blend+ELU -> h1b (bf16)
    k_gemm<<<dim3(4, 8, 8), 256, 0, stream>>>(xb, w0b, y, 480, 512, 512);
    k_reduce<<<2048, 256, 0, stream>>>(y, blend, b0, h1b, 512, 512, 1, 1);

    // 3) layer 1: [1024,512] x [8,512,512] -> y, then blend+ELU -> h2b (bf16)
    k_gemm<<<dim3(4, 8, 8), 256, 0, stream>>>(h1b, w1b, y, 512, 512, 512);
    k_reduce<<<2048, 256, 0, stream>>>(y, blend, b1, h2b, 512, 512, 1, 1);

    // 4) layer 2: [1024,512] x [8,311,512] -> y (ldy=320), blend+bias -> d_out (fp32)
    k_gemm<<<dim3(3, 8, 8), 256, 0, stream>>>(h2b, w2b, y, 512, 311, 320);
    k_reduce<<<1244, 256, 0, stream>>>(y, blend, b2, d_out, 311, 320, 0, 0);
}

// Round 2
// 72.312 us; speedup vs baseline: 1.1168x; 1.1168x over previous
//
#include <hip/hip_runtime.h>

typedef __attribute__((ext_vector_type(8))) short short8;
typedef __attribute__((ext_vector_type(4))) float f32x4;

__device__ __forceinline__ unsigned short f2bf(float f) {
    unsigned u = __builtin_bit_cast(unsigned, f);
    unsigned r = (u + 0x7FFFu + ((u >> 16) & 1u)) >> 16;
    return (unsigned short)r;
}
__device__ __forceinline__ float bf2f(unsigned short u) {
    unsigned v = ((unsigned)u) << 16;
    return __builtin_bit_cast(float, v);
}

// async global->LDS, 16B per lane; LDS dest = wave-uniform base + lane*16
__device__ __forceinline__ void gload16(const unsigned short* g, unsigned short* l) {
    __builtin_amdgcn_global_load_lds(
        (const __attribute__((address_space(1))) void*)g,
        (__attribute__((address_space(3))) void*)l,
        16, 0, 0);
}

#define WAITV(N) asm volatile("s_waitcnt vmcnt(" #N ")" ::: "memory")
#define BAR() do { asm volatile("" ::: "memory"); __builtin_amdgcn_s_barrier(); asm volatile("" ::: "memory"); } while (0)

// ---- fused fp32 -> bf16 conversion: x, w0, w1, w2 (8 elems/thread) ----
__global__ __launch_bounds__(256) void k_convert(
    const float* __restrict__ x,  const float* __restrict__ w0,
    const float* __restrict__ w1, const float* __restrict__ w2,
    unsigned short* __restrict__ xb,  unsigned short* __restrict__ w0b,
    unsigned short* __restrict__ w1b, unsigned short* __restrict__ w2b)
{
    const int nx  = (1024 * 480) / 8;
    const int nw0 = (8 * 512 * 480) / 8;
    const int nw1 = (8 * 512 * 512) / 8;
    const int nw2 = (8 * 311 * 512) / 8;
    int t = blockIdx.x * 256 + threadIdx.x;
    const float* src; unsigned short* dst;
    if (t < nx)                { src = x;  dst = xb;  }
    else if ((t -= nx)  < nw0) { src = w0; dst = w0b; }
    else if ((t -= nw0) < nw1) { src = w1; dst = w1b; }
    else if ((t -= nw1) < nw2) { src = w2; dst = w2b; }
    else return;
    const float4* s4 = (const float4*)src;
    float4 a = s4[2 * t], b = s4[2 * t + 1];
    union { unsigned short u[8]; int4 v; } r;
    r.u[0] = f2bf(a.x); r.u[1] = f2bf(a.y); r.u[2] = f2bf(a.z); r.u[3] = f2bf(a.w);
    r.u[4] = f2bf(b.x); r.u[5] = f2bf(b.y); r.u[6] = f2bf(b.z); r.u[7] = f2bf(b.w);
    ((int4*)dst)[t] = r.v;
}

// ---- batched per-expert NT GEMM with fused blend+bias epilogue ----
// A: [1024][K] bf16; W: [E][N][K] bf16; Y: [E][1024][ldy] bf16 = (A*W^T + bias)*blend
// 128x128 tile, 4 waves (2x2 of 64x64), BK=32, depth-3 pipelined glds staging.
__global__ __launch_bounds__(256) void k_gemm(
    const unsigned short* __restrict__ A,
    const unsigned short* __restrict__ W,
    const float* __restrict__ blend,   // [E][1024]
    const float* __restrict__ bias,    // [E][N]
    unsigned short* __restrict__ Y,
    int K, int N, int ldy)
{
    __shared__ unsigned short As[3][128][32];  // 24 KB
    __shared__ unsigned short Bs[3][128][32];  // 24 KB

    const int e  = blockIdx.z;
    const int bm = blockIdx.y * 128;
    const int on = blockIdx.x * 128;
    const int t  = threadIdx.x;
    const int lane = t & 63;
    const int w  = t >> 6;
    const int wr = w >> 1, wc = w & 1;

    const unsigned short* Wt = W + (size_t)e * N * K;

    // staging coords: wave w covers rows [w*16, w*16+16) (q=0) and +64 (q=1);
    // lane l -> row +l/4, k-col (l&3)*8. Wave writes contiguous 1024B in LDS.
    const int sr = lane >> 2;
    const int sc = (lane & 3) * 8;
    const int ra0 = w * 16 + sr, ra1 = 64 + w * 16 + sr;
    int rb0 = on + ra0; if (rb0 > N - 1) rb0 = N - 1;
    int rb1 = on + ra1; if (rb1 > N - 1) rb1 = N - 1;
    const unsigned short* gA0 = A  + (size_t)(bm + ra0) * K + sc;
    const unsigned short* gA1 = A  + (size_t)(bm + ra1) * K + sc;
    const unsigned short* gB0 = Wt + (size_t)rb0 * K + sc;
    const unsigned short* gB1 = Wt + (size_t)rb1 * K + sc;

    const int ktn = K / 32;

#define STAGE(buf, kt) do { int _k0 = (kt) * 32;                       \
        gload16(gA0 + _k0, &As[(buf)][w * 16][0]);                     \
        gload16(gA1 + _k0, &As[(buf)][64 + w * 16][0]);                \
        gload16(gB0 + _k0, &Bs[(buf)][w * 16][0]);                     \
        gload16(gB1 + _k0, &Bs[(buf)][64 + w * 16][0]); } while (0)

    f32x4 acc[4][4] = {};

    STAGE(0, 0); STAGE(1, 1); STAGE(2, 2);   // 12 loads in flight / thread

    int cur = 0;
    for (int kt = 0; kt < ktn; ++kt) {
        int ahead = ktn - 1 - kt;            // tiles staged beyond current
        if (ahead >= 2)      WAITV(8);       // wait own 4 loads of tile kt
        else if (ahead == 1) WAITV(4);
        else                 WAITV(0);
        BAR();                               // buffer cur ready for all waves

        short8 af[4], bfr[4];
        #pragma unroll
        for (int fm = 0; fm < 4; ++fm)
            af[fm] = *(const short8*)&As[cur][wr * 64 + fm * 16 + (lane & 15)][(lane >> 4) * 8];
        #pragma unroll
        for (int fn = 0; fn < 4; ++fn)
            bfr[fn] = *(const short8*)&Bs[cur][wc * 64 + fn * 16 + (lane & 15)][(lane >> 4) * 8];
        #pragma unroll
        for (int fm = 0; fm < 4; ++fm)
            #pragma unroll
            for (int fn = 0; fn < 4; ++fn)
                acc[fm][fn] = __builtin_amdgcn_mfma_f32_16x16x32_bf16(
                    af[fm], bfr[fn], acc[fm][fn], 0, 0, 0);

        BAR();                               // all waves done reading buf cur
        if (kt + 3 < ktn) STAGE(cur, kt + 3);
        cur = (cur == 2) ? 0 : cur + 1;
    }
#undef STAGE

    // epilogue: D j = lane&15, i = 4*(lane>>4)+r ; y = (acc + bias_e[j]) * blend_e[i]
    const float* blendE = blend + e * 1024;
    const float* biasE  = bias + (size_t)e * N;
    unsigned short* Ye  = Y + (size_t)e * 1024 * ldy;
    #pragma unroll
    for (int fm = 0; fm < 4; ++fm) {
        int i0 = bm + wr * 64 + fm * 16 + (lane >> 4) * 4;
        float4 bl = *(const float4*)&blendE[i0];
        #pragma unroll
        for (int fn = 0; fn < 4; ++fn) {
            int j = on + wc * 64 + fn * 16 + (lane & 15);
            if (j < N) {
                float bs = biasE[j];
                #pragma unroll
                for (int r = 0; r < 4; ++r)
                    Ye[(size_t)(i0 + r) * ldy + j] = f2bf((acc[fm][fn][r] + bs) * ((&bl.x)[r]));
            }
        }
    }
}

// ---- sum 8 bf16 partials + optional ELU ----
__global__ __launch_bounds__(256) void k_reduce(
    const unsigned short* __restrict__ Y,  // [8][1024][ldy] bf16
    void* __restrict__ out,
    int N, int ldy, int act, int out_bf16)
{
    int b = blockIdx.y;
    int o = blockIdx.x * 256 + threadIdx.x;
    if (o >= N) return;
    size_t base = (size_t)b * ldy + o;
    size_t estride = (size_t)1024 * ldy;
    float s = 0.f;
    #pragma unroll
    for (int e = 0; e < 8; ++e) s += bf2f(Y[base + (size_t)e * estride]);
    if (act) s = (s > 0.f) ? s : expm1f(s);
    if (out_bf16) ((unsigned short*)out)[(size_t)b * N + o] = f2bf(s);
    else          ((float*)out)[(size_t)b * N + o] = s;
}

extern "C" void kernel_launch(void* const* d_in, const int* in_sizes, int n_in,
                              void* d_out, int out_size, void* d_ws, size_t ws_size,
                              hipStream_t stream) {
    const float* x     = (const float*)d_in[0];
    const float* blend = (const float*)d_in[1];
    const float* w0    = (const float*)d_in[2];
    const float* b0    = (const float*)d_in[3];
    const float* w1    = (const float*)d_in[4];
    const float* b1    = (const float*)d_in[5];
    const float* w2    = (const float*)d_in[6];
    const float* b2    = (const float*)d_in[7];

    char* ws = (char*)d_ws;
    unsigned short* xb  = (unsigned short*)(ws + 0);          //   983,040
    unsigned short* w0b = (unsigned short*)(ws + 983040);     // 3,932,160
    unsigned short* w1b = (unsigned short*)(ws + 4915200);    // 4,194,304
    unsigned short* w2b = (unsigned short*)(ws + 9109504);    // 2,547,712
    unsigned short* h1b = (unsigned short*)(ws + 11657216);   // 1,048,576
    unsigned short* h2b = (unsigned short*)(ws + 12705792);   // 1,048,576
    unsigned short* yb  = (unsigned short*)(ws + 13754368);   // 8,388,608 (bf16 partials)
    // total ~22.1 MB

    k_convert<<<2846, 256, 0, stream>>>(x, w0, w1, w2, xb, w0b, w1b, w2b);

    // layer 0: K=480, N=512
    k_gemm<<<dim3(4, 8, 8), 256, 0, stream>>>(xb, w0b, blend, b0, yb, 480, 512, 512);
    k_reduce<<<dim3(2, 1024), 256, 0, stream>>>(yb, h1b, 512, 512, 1, 1);

    // layer 1: K=512, N=512
    k_gemm<<<dim3(4, 8, 8), 256, 0, stream>>>(h1b, w1b, blend, b1, yb, 512, 512, 512);
    k_reduce<<<dim3(2, 1024), 256, 0, stream>>>(yb, h2b, 512, 512, 1, 1);

    // layer 2: K=512, N=311 (ldy=320), no ELU, fp32 out
    k_gemm<<<dim3(3, 8, 8), 256, 0, stream>>>(h2b, w2b, blend, b2, yb, 512, 311, 320);
    k_reduce<<<dim3(2, 1024), 256, 0, stream>>>(yb, d_out, 311, 320, 0, 0);
}

// Round 4
// 67.315 us; speedup vs baseline: 1.1997x; 1.0742x over previous
//
#include <hip/hip_runtime.h>

typedef __attribute__((ext_vector_type(8))) short short8;
typedef __attribute__((ext_vector_type(4))) float f32x4;

__device__ __forceinline__ unsigned short f2bf(float f) {
    unsigned u = __builtin_bit_cast(unsigned, f);
    unsigned r = (u + 0x7FFFu + ((u >> 16) & 1u)) >> 16;
    return (unsigned short)r;
}
__device__ __forceinline__ float bf2f(unsigned short u) {
    unsigned v = ((unsigned)u) << 16;
    return __builtin_bit_cast(float, v);
}

// async global->LDS, 16B per lane; LDS dest = wave-uniform base + lane*16
__device__ __forceinline__ void gload16(const unsigned short* g, unsigned short* l) {
    __builtin_amdgcn_global_load_lds(
        (const __attribute__((address_space(1))) void*)g,
        (__attribute__((address_space(3))) void*)l,
        16, 0, 0);
}

#define WAITV(N) asm volatile("s_waitcnt vmcnt(" #N ")" ::: "memory")
#define BAR() do { asm volatile("" ::: "memory"); __builtin_amdgcn_s_barrier(); asm volatile("" ::: "memory"); } while (0)

// ---- fused fp32 -> bf16 conversion: x, w0, w1, w2 (8 elems/thread) ----
__global__ __launch_bounds__(256) void k_convert(
    const float* __restrict__ x,  const float* __restrict__ w0,
    const float* __restrict__ w1, const float* __restrict__ w2,
    unsigned short* __restrict__ xb,  unsigned short* __restrict__ w0b,
    unsigned short* __restrict__ w1b, unsigned short* __restrict__ w2b)
{
    const int nx  = (1024 * 480) / 8;
    const int nw0 = (8 * 512 * 480) / 8;
    const int nw1 = (8 * 512 * 512) / 8;
    const int nw2 = (8 * 311 * 512) / 8;
    int t = blockIdx.x * 256 + threadIdx.x;
    const float* src; unsigned short* dst;
    if (t < nx)                { src = x;  dst = xb;  }
    else if ((t -= nx)  < nw0) { src = w0; dst = w0b; }
    else if ((t -= nw0) < nw1) { src = w1; dst = w1b; }
    else if ((t -= nw1) < nw2) { src = w2; dst = w2b; }
    else return;
    const float4* s4 = (const float4*)src;
    float4 a = s4[2 * t], b = s4[2 * t + 1];
    union { unsigned short u[8]; int4 v; } r;
    r.u[0] = f2bf(a.x); r.u[1] = f2bf(a.y); r.u[2] = f2bf(a.z); r.u[3] = f2bf(a.w);
    r.u[4] = f2bf(b.x); r.u[5] = f2bf(b.y); r.u[6] = f2bf(b.z); r.u[7] = f2bf(b.w);
    ((int4*)dst)[t] = r.v;
}

// ---- batched per-expert NT GEMM with fused blend+bias epilogue ----
// A: [1024][K] bf16; W: [E][N][K] bf16; Y: [E][1024][ldy] bf16 = (A*W^T + bias)*blend
// 128x128 block tile, 8 waves (2x4 of 64x32), BK=32, depth-3 pipelined glds staging.
// 8 waves/CU = 2 waves/SIMD (vs 1 in the 4-wave version) for latency hiding.
__global__ __launch_bounds__(512) void k_gemm(
    const unsigned short* __restrict__ A,
    const unsigned short* __restrict__ W,
    const float* __restrict__ blend,   // [E][1024]
    const float* __restrict__ bias,    // [E][N]
    unsigned short* __restrict__ Y,
    int K, int N, int ldy)
{
    __shared__ unsigned short As[3][128][32];  // 24 KB
    __shared__ unsigned short Bs[3][128][32];  // 24 KB

    const int e  = blockIdx.z;
    const int bm = blockIdx.y * 128;
    const int on = blockIdx.x * 128;
    const int t  = threadIdx.x;
    const int lane = t & 63;
    const int w  = t >> 6;          // 0..7
    const int wr = w >> 2;          // 0..1  (64-row band)
    const int wc = w & 3;           // 0..3  (32-col band)

    const unsigned short* Wt = W + (size_t)e * N * K;

    // staging: wave w covers rows [w*16, w*16+16); lane l -> row +l/4, k-col (l&3)*8.
    // One A-chunk + one B-chunk per thread per tile (2 gloads).
    const int sr = lane >> 2;
    const int sc = (lane & 3) * 8;
    const int ra = w * 16 + sr;
    int rb = on + ra; if (rb > N - 1) rb = N - 1;     // clamp for N=311 tail tile
    const unsigned short* gA = A  + (size_t)(bm + ra) * K + sc;
    const unsigned short* gB = Wt + (size_t)rb * K + sc;

    const int ktn = K / 32;

#define STAGE(buf, kt) do { int _k0 = (kt) * 32;                       \
        gload16(gA + _k0, &As[(buf)][w * 16][0]);                      \
        gload16(gB + _k0, &Bs[(buf)][w * 16][0]); } while (0)

    f32x4 acc[4][2] = {};

    STAGE(0, 0); STAGE(1, 1); STAGE(2, 2);   // 6 loads in flight / thread

    int cur = 0;
    for (int kt = 0; kt < ktn; ++kt) {
        int ahead = ktn - 1 - kt;
        if (ahead >= 2)      WAITV(4);       // own 2 loads of tile kt complete
        else if (ahead == 1) WAITV(2);
        else                 WAITV(0);
        BAR();                               // buffer cur ready for all waves

        short8 af[4], bfr[2];
        #pragma unroll
        for (int fm = 0; fm < 4; ++fm)
            af[fm] = *(const short8*)&As[cur][wr * 64 + fm * 16 + (lane & 15)][(lane >> 4) * 8];
        #pragma unroll
        for (int fn = 0; fn < 2; ++fn)
            bfr[fn] = *(const short8*)&Bs[cur][wc * 32 + fn * 16 + (lane & 15)][(lane >> 4) * 8];
        #pragma unroll
        for (int fm = 0; fm < 4; ++fm)
            #pragma unroll
            for (int fn = 0; fn < 2; ++fn)
                acc[fm][fn] = __builtin_amdgcn_mfma_f32_16x16x32_bf16(
                    af[fm], bfr[fn], acc[fm][fn], 0, 0, 0);

        BAR();                               // all waves done reading buf cur
        if (kt + 3 < ktn) STAGE(cur, kt + 3);
        cur = (cur == 2) ? 0 : cur + 1;
    }
#undef STAGE

    // epilogue: D j = lane&15, i = 4*(lane>>4)+r ; y = (acc + bias_e[j]) * blend_e[i]
    const float* blendE = blend + e * 1024;
    const float* biasE  = bias + (size_t)e * N;
    unsigned short* Ye  = Y + (size_t)e * 1024 * ldy;
    #pragma unroll
    for (int fm = 0; fm < 4; ++fm) {
        int i0 = bm + wr * 64 + fm * 16 + (lane >> 4) * 4;
        float4 bl = *(const float4*)&blendE[i0];
        #pragma unroll
        for (int fn = 0; fn < 2; ++fn) {
            int j = on + wc * 32 + fn * 16 + (lane & 15);
            if (j < N) {
                float bs = biasE[j];
                #pragma unroll
                for (int r = 0; r < 4; ++r)
                    Ye[(size_t)(i0 + r) * ldy + j] = f2bf((acc[fm][fn][r] + bs) * ((&bl.x)[r]));
            }
        }
    }
}

// ---- sum 8 bf16 partial planes + ELU, 8 outputs/thread, bf16 out (N=512) ----
__global__ __launch_bounds__(256) void k_reduce8(
    const unsigned short* __restrict__ Y,  // [8][1024][512] bf16
    unsigned short* __restrict__ out)      // [1024][512] bf16
{
    int idx = blockIdx.x * 256 + threadIdx.x;     // 65536 threads
    int b  = idx >> 6;
    int o0 = (idx & 63) * 8;
    size_t base = (size_t)b * 512 + o0;
    float s[8] = {};
    #pragma unroll
    for (int e = 0; e < 8; ++e) {
        int4 v = *(const int4*)&Y[base + (size_t)e * 1024 * 512];
        const unsigned short* u = (const unsigned short*)&v;
        #pragma unroll
        for (int r = 0; r < 8; ++r) s[r] += bf2f(u[r]);
    }
    union { unsigned short u[8]; int4 v; } rr;
    #pragma unroll
    for (int r = 0; r < 8; ++r) {
        float v = (s[r] > 0.f) ? s[r] : expm1f(s[r]);
        rr.u[r] = f2bf(v);
    }
    *(int4*)&out[base] = rr.v;
}

// ---- final reduce: N=311 (planes ldy=320), fp32 out, no activation ----
__global__ __launch_bounds__(256) void k_reduce_last(
    const unsigned short* __restrict__ Y,  // [8][1024][320] bf16
    float* __restrict__ out)               // [1024][311] fp32
{
    int idx = blockIdx.x * 256 + threadIdx.x;     // 1024*40 = 40960 threads
    if (idx >= 1024 * 40) return;
    int b  = idx / 40;
    int o0 = (idx - b * 40) * 8;                  // 0..312
    size_t base = (size_t)b * 320 + o0;
    float s[8] = {};
    #pragma unroll
    for (int e = 0; e < 8; ++e) {
        int4 v = *(const int4*)&Y[base + (size_t)e * 1024 * 320];
        const unsigned short* u = (const unsigned short*)&v;
        #pragma unroll
        for (int r = 0; r < 8; ++r) s[r] += bf2f(u[r]);
    }
    #pragma unroll
    for (int r = 0; r < 8; ++r)
        if (o0 + r < 311) out[(size_t)b * 311 + o0 + r] = s[r];
}

extern "C" void kernel_launch(void* const* d_in, const int* in_sizes, int n_in,
                              void* d_out, int out_size, void* d_ws, size_t ws_size,
                              hipStream_t stream) {
    const float* x     = (const float*)d_in[0];
    const float* blend = (const float*)d_in[1];
    const float* w0    = (const float*)d_in[2];
    const float* b0    = (const float*)d_in[3];
    const float* w1    = (const float*)d_in[4];
    const float* b1    = (const float*)d_in[5];
    const float* w2    = (const float*)d_in[6];
    const float* b2    = (const float*)d_in[7];

    char* ws = (char*)d_ws;
    unsigned short* xb  = (unsigned short*)(ws + 0);          //   983,040
    unsigned short* w0b = (unsigned short*)(ws + 983040);     // 3,932,160
    unsigned short* w1b = (unsigned short*)(ws + 4915200);    // 4,194,304
    unsigned short* w2b = (unsigned short*)(ws + 9109504);    // 2,547,712
    unsigned short* h1b = (unsigned short*)(ws + 11657216);   // 1,048,576
    unsigned short* h2b = (unsigned short*)(ws + 12705792);   // 1,048,576
    unsigned short* yb  = (unsigned short*)(ws + 13754368);   // 8,388,608 (bf16 partials)

    k_convert<<<2846, 256, 0, stream>>>(x, w0, w1, w2, xb, w0b, w1b, w2b);

    // layer 0: K=480, N=512
    k_gemm<<<dim3(4, 8, 8), 512, 0, stream>>>(xb, w0b, blend, b0, yb, 480, 512, 512);
    k_reduce8<<<256, 256, 0, stream>>>(yb, h1b);

    // layer 1: K=512, N=512
    k_gemm<<<dim3(4, 8, 8), 512, 0, stream>>>(h1b, w1b, blend, b1, yb, 512, 512, 512);
    k_reduce8<<<256, 256, 0, stream>>>(yb, h2b);

    // layer 2: K=512, N=311 (ldy=320), no ELU, fp32 out
    k_gemm<<<dim3(3, 8, 8), 512, 0, stream>>>(h2b, w2b, blend, b2, yb, 512, 311, 320);
    k_reduce_last<<<160, 256, 0, stream>>>(yb, (float*)d_out);
}